// Round 8
// baseline (61707.947 us; speedup 1.0000x reference)
//
#include <hip/hip_runtime.h>
#include <hip/hip_bf16.h>
#include <math.h>

// Problem constants (from reference)
#define NA   4096      // num agents / edges
#define FDIM 512
#define SDIM 6
#define HID  20
#define GDIM 2048      // 4*FDIM (LSTM gate width)
#define LWG  32        // WGs per LSTM role in the persistent pair kernel

typedef unsigned long long u64;

__device__ __forceinline__ float sigf(float x) { return 1.0f / (1.0f + __expf(-x)); }
__device__ __forceinline__ float tanh_fast(float x) {
    float e = __expf(2.0f * x);
    return 1.0f - 2.0f / (e + 1.0f);
}

__device__ __forceinline__ void atomicMaxF(float* addr, float v) {
    if (v >= 0.0f) atomicMax((int*)addr, __float_as_int(v));
    else           atomicMin((unsigned int*)addr, __float_as_uint(v));
}

// ---------------------------------------------------------------------------
// phi MLP, fused per edge: msg = [xin[src] | states[src]-states[dst]] (518)
// ---------------------------------------------------------------------------
__global__ void __launch_bounds__(256)
phi_fused(const float* __restrict__ xin, const float* __restrict__ states,
          const int* __restrict__ src, const int* __restrict__ dst,
          const float* __restrict__ w0, const float* __restrict__ b0,
          const float* __restrict__ w1, const float* __restrict__ b1,
          const float* __restrict__ w2, const float* __restrict__ b2,
          float* __restrict__ phi)
{
    int e = blockIdx.x, tid = threadIdx.x;
    __shared__ float msgv[FDIM + SDIM];
    __shared__ float red[240];
    __shared__ float hb1[HID];
    __shared__ float hb2[HID];
    int s = src[e], d = dst[e];
    for (int i = tid; i < FDIM; i += 256) msgv[i] = xin[(size_t)s * FDIM + i];
    if (tid < SDIM) msgv[FDIM + tid] = states[s * SDIM + tid] - states[d * SDIM + tid];
    __syncthreads();
    if (tid < 240) {
        int col = tid / 12, sg = tid % 12;
        int k0 = sg * 44, k1 = min(FDIM + SDIM, k0 + 44);
        float acc = 0.0f;
        for (int k = k0; k < k1; k++) acc += msgv[k] * w0[k * HID + col];
        red[tid] = acc;
    }
    __syncthreads();
    if (tid < HID) {
        float a = b0[tid];
#pragma unroll
        for (int q = 0; q < 12; q++) a += red[tid * 12 + q];
        hb1[tid] = fmaxf(a, 0.0f);
    }
    __syncthreads();
    if (tid < HID) {
        float a = b1[tid];
#pragma unroll
        for (int k = 0; k < HID; k++) a += hb1[k] * w1[k * HID + tid];
        hb2[tid] = fmaxf(a, 0.0f);
    }
    __syncthreads();
    for (int c = tid; c < FDIM; c += 256) {
        float a = b2[c];
#pragma unroll
        for (int k = 0; k < HID; k++) a += hb2[k] * w2[k * FDIM + c];
        phi[(size_t)e * FDIM + c] = a;
    }
}

// ---------------------------------------------------------------------------
// fp32 tiled GEMM: C[M,N] = A[M,K] @ B[K,N] + bias[N]; A split at col splitA.
// 128x128 tile, 256 threads, 8x8 microtile. blockIdx.z picks (B,bias,C).
// ---------------------------------------------------------------------------
struct Ptrs4 {
    const float* B[4];
    const float* bias[4];
    float* C[4];
};

__global__ void __launch_bounds__(256)
gemm128(const float* __restrict__ A1, int lda1,
        const float* __restrict__ A2, int lda2, int splitA,
        Ptrs4 p, int M, int N, int K)
{
    __shared__ float a_lds[16][132];
    __shared__ float b_lds[16][132];
    const float* __restrict__ B    = p.B[blockIdx.z];
    const float* __restrict__ bias = p.bias[blockIdx.z];
    float* __restrict__ C          = p.C[blockIdx.z];
    const int tid = threadIdx.x;
    const int m0 = blockIdx.y * 128, n0 = blockIdx.x * 128;
    const int ar = tid >> 2, ak4 = (tid & 3) * 4;
    const int br = tid >> 5, bc4 = (tid & 31) * 4;
    const int ty = tid >> 4, tx = tid & 15;
    float acc[8][8] = {};

    for (int kt = 0; kt < K; kt += 16) {
        int ak = kt + ak4;
        if (ak < splitA) {
            const float* r0 = A1 + (size_t)(m0 + ar) * lda1 + ak;
            const float* r1 = A1 + (size_t)(m0 + ar + 64) * lda1 + ak;
            float4 a0 = *(const float4*)r0;
            float4 a1 = *(const float4*)r1;
            a_lds[ak4 + 0][ar] = a0.x; a_lds[ak4 + 1][ar] = a0.y;
            a_lds[ak4 + 2][ar] = a0.z; a_lds[ak4 + 3][ar] = a0.w;
            a_lds[ak4 + 0][ar + 64] = a1.x; a_lds[ak4 + 1][ar + 64] = a1.y;
            a_lds[ak4 + 2][ar + 64] = a1.z; a_lds[ak4 + 3][ar + 64] = a1.w;
        } else {
            int acol = ak - splitA;
            const float* r0 = A2 + (size_t)(m0 + ar) * lda2 + acol;
            const float* r1 = A2 + (size_t)(m0 + ar + 64) * lda2 + acol;
            float4 a0 = *(const float4*)r0;
            float4 a1 = *(const float4*)r1;
            a_lds[ak4 + 0][ar] = a0.x; a_lds[ak4 + 1][ar] = a0.y;
            a_lds[ak4 + 2][ar] = a0.z; a_lds[ak4 + 3][ar] = a0.w;
            a_lds[ak4 + 0][ar + 64] = a1.x; a_lds[ak4 + 1][ar + 64] = a1.y;
            a_lds[ak4 + 2][ar + 64] = a1.z; a_lds[ak4 + 3][ar + 64] = a1.w;
        }
        {
            float4 b0v = *(const float4*)(B + (size_t)(kt + br) * N + n0 + bc4);
            float4 b1v = *(const float4*)(B + (size_t)(kt + br + 8) * N + n0 + bc4);
            *(float4*)&b_lds[br][bc4] = b0v;
            *(float4*)&b_lds[br + 8][bc4] = b1v;
        }
        __syncthreads();
#pragma unroll
        for (int kk = 0; kk < 16; kk++) {
            float av[8], bv[8];
            *(float4*)&av[0] = *(const float4*)&a_lds[kk][ty * 4];
            *(float4*)&av[4] = *(const float4*)&a_lds[kk][64 + ty * 4];
            *(float4*)&bv[0] = *(const float4*)&b_lds[kk][tx * 4];
            *(float4*)&bv[4] = *(const float4*)&b_lds[kk][64 + tx * 4];
#pragma unroll
            for (int i = 0; i < 8; i++)
#pragma unroll
                for (int j = 0; j < 8; j++)
                    acc[i][j] += av[i] * bv[j];
        }
        __syncthreads();
    }

    float4 bb0 = *(const float4*)(bias + n0 + tx * 4);
    float4 bb1 = *(const float4*)(bias + n0 + 64 + tx * 4);
    const float bbs0[4] = { bb0.x, bb0.y, bb0.z, bb0.w };
    const float bbs1[4] = { bb1.x, bb1.y, bb1.z, bb1.w };
#pragma unroll
    for (int i = 0; i < 8; i++) {
        int row = m0 + ((i < 4) ? (ty * 4 + i) : (64 + ty * 4 + i - 4));
        float4 o0, o1;
        o0.x = acc[i][0] + bbs0[0]; o0.y = acc[i][1] + bbs0[1];
        o0.z = acc[i][2] + bbs0[2]; o0.w = acc[i][3] + bbs0[3];
        o1.x = acc[i][4] + bbs1[0]; o1.y = acc[i][5] + bbs1[1];
        o1.z = acc[i][6] + bbs1[2]; o1.w = acc[i][7] + bbs1[3];
        *(float4*)&C[(size_t)row * N + n0 + tx * 4] = o0;
        *(float4*)&C[(size_t)row * N + n0 + 64 + tx * 4] = o1;
    }
}

// ---------------------------------------------------------------------------
// attention (generic segment softmax; with dst=arange it is singleton/exact)
// ---------------------------------------------------------------------------
__global__ void att_init(float* __restrict__ m, float* __restrict__ ssum)
{
    int i = blockIdx.x * blockDim.x + threadIdx.x;
    if (i < NA) { m[i] = -INFINITY; ssum[i] = 0.0f; }
}

__global__ void att_logits(const float* __restrict__ q, const float* __restrict__ k,
                           const int* __restrict__ src, const int* __restrict__ dst,
                           float* __restrict__ logits, float* __restrict__ m)
{
    int e = blockIdx.x, tid = threadIdx.x;
    int s = src[e], d = dst[e];
    const float4* qr = (const float4*)(q + (size_t)d * FDIM);
    const float4* kr = (const float4*)(k + (size_t)s * FDIM);
    float acc = 0.0f;
    for (int i = tid; i < FDIM / 4; i += 64) {
        float4 a = qr[i], b = kr[i];
        acc += a.x * b.x + a.y * b.y + a.z * b.z + a.w * b.w;
    }
    for (int off = 32; off; off >>= 1) acc += __shfl_down(acc, off);
    if (tid == 0) {
        float v = acc * 0.04419417382415922f;   // 1/sqrt(512)
        logits[e] = v;
        atomicMaxF(&m[d], v);
    }
}

__global__ void att_expsum(const float* __restrict__ logits, const float* __restrict__ m,
                           const int* __restrict__ dst,
                           float* __restrict__ ebuf, float* __restrict__ ssum)
{
    int e = blockIdx.x * blockDim.x + threadIdx.x;
    if (e < NA) {
        float v = __expf(logits[e] - m[dst[e]]);
        ebuf[e] = v;
        atomicAdd(&ssum[dst[e]], v);
    }
}

__global__ void att_scatter(const float* __restrict__ v, const int* __restrict__ src,
                            const int* __restrict__ dst, const float* __restrict__ ebuf,
                            const float* __restrict__ ssum, float* __restrict__ aggr)
{
    int e = blockIdx.x, tid = threadIdx.x;
    int s = src[e], d = dst[e];
    float alpha = ebuf[e] / ssum[d];
    const float* vr = v + (size_t)s * FDIM;
    float* ar = aggr + (size_t)d * FDIM;
    for (int c = tid; c < FDIM; c += 256) atomicAdd(&ar[c], alpha * vr[c]);
}

// ---------------------------------------------------------------------------
// Pipelined 2-layer LSTM scan, barrier-free steady state. 64 WGs x 512 thr.
// Per wave: own 2 h-dims (lane=(seg<<3)|c, shfl k-reduce, parallel gates).
// Publish: lanes 0,1 -> hstage; lane 0 release-stores per-wave step flag;
//   wave 0 acquire-spins on 8 flags then issues ONE 128B full-line tagged
//   store (and 64B xout in role B). No __syncthreads in the loop.
// Consume: EACH WAVE polls all h words itself (8/16 coalesced 512B tagged
//   loads, issued together, verified late-data-first) into its PRIVATE
//   padded LDS region -> no cross-wave LDS dependency -> no barrier.
// Tag protocol identical to R7 (proven): word = (tag0/1 + t + 1)<<32 | bits.
// ---------------------------------------------------------------------------
__global__ void __launch_bounds__(512, 2)
lstm_pair(const float* __restrict__ pre0, const float* __restrict__ whh0,
          const float* __restrict__ wih1, const float* __restrict__ whh1,
          const float* __restrict__ b1,
          float* __restrict__ xout,
          u64* __restrict__ hfull,
          u64* __restrict__ hbuf1,
          unsigned int tag0, unsigned int tag1, int T)
{
    const int wg = blockIdx.x;
    const bool roleB = wg >= LWG;
    const int w = wg & (LWG - 1);
    const int tid = threadIdx.x;
    const int lane = tid & 63;
    const int wv = tid >> 6;               // wave 0..7
    const int c = lane & 7;                // gate-column slot
    const int seg = lane >> 3;             // k-segment 0..7
    const int gate = c >> 1;               // 0=i 1=f 2=g 3=o
    const int dimoff = c & 1;
    const int hd = w * 16 + wv * 2 + dimoff;   // owned h dim
    const int j = gate * 512 + hd;             // gate column index

    // per-wave private h copies: [buf parity][wave][group*68 + idx]
    // role A uses groups 0..7 (h, 512), role B groups 0..15 ([h0;h1], 1024)
    __shared__ float priv[2][8][1088];
    __shared__ float hstage[16];
    __shared__ unsigned flags[8 * 16];     // flags[wv*16], monotonic step count

    {   // zero LDS once
        float* pz = &priv[0][0][0];
        for (int i = tid; i < 2 * 8 * 1088; i += 512) pz[i] = 0.0f;
        if (tid < 128) flags[tid] = 0u;
    }

    float wreg[128];
    if (!roleB) {
        const float* wc = whh0 + (size_t)(seg * 64) * GDIM + j;
#pragma unroll
        for (int kk = 0; kk < 64; kk++) wreg[kk] = wc[(size_t)kk * GDIM];
    } else {
        // concat [h0 ; h1] weight column: k<512 -> wih1, else whh1
#pragma unroll
        for (int kk = 0; kk < 128; kk++) {
            int k = seg * 128 + kk;
            wreg[kk] = (k < 512) ? wih1[(size_t)k * GDIM + j]
                                 : whh1[(size_t)(k - 512) * GDIM + j];
        }
    }
    __syncthreads();   // LDS zero visible to all (only barrier in the kernel)

    const int gbase = (lane & 56) | dimoff;   // shfl gather base
    const int fi = (lane < 8) ? lane : 0;     // publisher spin index

    if (!roleB) {
        float cst = 0.0f;
        float pre_nxt = pre0[j];
        int p = 0;
        for (int t = 0; t < T; t++) {
            const float* hb = &priv[p][wv][seg * 68];
            float a0 = 0, a1 = 0, a2 = 0, a3 = 0;
#pragma unroll
            for (int kk = 0; kk < 64; kk += 4) {
                float4 hv = *(const float4*)(hb + kk);
                a0 += wreg[kk + 0] * hv.x;
                a1 += wreg[kk + 1] * hv.y;
                a2 += wreg[kk + 2] * hv.z;
                a3 += wreg[kk + 3] * hv.w;
            }
            float tot = (a0 + a1) + (a2 + a3);
            tot += __shfl_xor(tot, 8);
            tot += __shfl_xor(tot, 16);
            tot += __shfl_xor(tot, 32);
            tot += pre_nxt;
            if (t + 1 < T) pre_nxt = pre0[(size_t)(t + 1) * GDIM + j];  // prefetch
            float nl = (gate == 2) ? tanh_fast(tot) : sigf(tot);
            float ff = __shfl(nl, gbase | 2);
            float gg = __shfl(nl, gbase | 4);
            float oo = __shfl(nl, gbase | 6);
            if (lane < 2) {
                cst = ff * cst + nl * gg;       // nl = sig(i) on lanes 0,1
                hstage[wv * 2 + lane] = oo * tanh_fast(cst);
            }
            if (lane == 0)
                __hip_atomic_store(&flags[wv * 16], (unsigned)(t + 1),
                                   __ATOMIC_RELEASE, __HIP_MEMORY_SCOPE_WORKGROUP);
            if (wv == 0) {   // publisher: spin flags, full-line publish
                while (__hip_atomic_load(&flags[fi * 16], __ATOMIC_ACQUIRE,
                                         __HIP_MEMORY_SCOPE_WORKGROUP) < (unsigned)(t + 1)) {}
                if (lane < 16) {
                    u64 word = ((u64)(tag0 + (unsigned)t + 1u) << 32) |
                               (u64)__float_as_uint(hstage[lane]);
                    __hip_atomic_store(&hfull[(size_t)t * 512 + w * 16 + lane], word,
                                       __ATOMIC_RELAXED, __HIP_MEMORY_SCOPE_AGENT);
                }
            }
            if (t + 1 < T) {
                const u64 want = (u64)(tag0 + (unsigned)t + 1u);
                const u64* base = &hfull[(size_t)t * 512 + lane];
                u64 vv[8];
#pragma unroll
                for (int k = 0; k < 8; k++)
                    vv[k] = __hip_atomic_load(base + k * 64, __ATOMIC_RELAXED,
                                              __HIP_MEMORY_SCOPE_AGENT);
                float* dst_ = &priv[p ^ 1][wv][0];
#pragma unroll
                for (int k = 0; k < 8; k++) {
                    while ((vv[k] >> 32) != want)
                        vv[k] = __hip_atomic_load(base + k * 64, __ATOMIC_RELAXED,
                                                  __HIP_MEMORY_SCOPE_AGENT);
                    dst_[k * 68 + lane] = __uint_as_float((unsigned)vv[k]);
                }
                __threadfence_block();
                p ^= 1;
            }
        }
    } else {
        float cst = 0.0f;
        float bias = b1[j];
        int p = 0;
        {   // prologue: poll h0(0) into priv[0] groups 0..7; h1(-1)=0 via zero-init
            const u64 want = (u64)(tag0 + 1u);
            const u64* base = &hfull[lane];
            u64 vv[8];
#pragma unroll
            for (int k = 0; k < 8; k++)
                vv[k] = __hip_atomic_load(base + k * 64, __ATOMIC_RELAXED,
                                          __HIP_MEMORY_SCOPE_AGENT);
            float* dst_ = &priv[0][wv][0];
#pragma unroll
            for (int k = 0; k < 8; k++) {
                while ((vv[k] >> 32) != want)
                    vv[k] = __hip_atomic_load(base + k * 64, __ATOMIC_RELAXED,
                                              __HIP_MEMORY_SCOPE_AGENT);
                dst_[k * 68 + lane] = __uint_as_float((unsigned)vv[k]);
            }
            __threadfence_block();
        }
        for (int t = 0; t < T; t++) {
            const float* hb = &priv[p][wv][seg * 136];   // groups 2seg, 2seg+1
            float a0 = 0, a1 = 0, a2 = 0, a3 = 0;
#pragma unroll
            for (int kk = 0; kk < 64; kk += 4) {
                float4 hv = *(const float4*)(hb + kk);
                a0 += wreg[kk + 0] * hv.x;
                a1 += wreg[kk + 1] * hv.y;
                a2 += wreg[kk + 2] * hv.z;
                a3 += wreg[kk + 3] * hv.w;
            }
#pragma unroll
            for (int kk = 0; kk < 64; kk += 4) {
                float4 hv = *(const float4*)(hb + 68 + kk);
                a0 += wreg[64 + kk + 0] * hv.x;
                a1 += wreg[64 + kk + 1] * hv.y;
                a2 += wreg[64 + kk + 2] * hv.z;
                a3 += wreg[64 + kk + 3] * hv.w;
            }
            float tot = (a0 + a1) + (a2 + a3);
            tot += __shfl_xor(tot, 8);
            tot += __shfl_xor(tot, 16);
            tot += __shfl_xor(tot, 32);
            tot += bias;
            float nl = (gate == 2) ? tanh_fast(tot) : sigf(tot);
            float ff = __shfl(nl, gbase | 2);
            float gg = __shfl(nl, gbase | 4);
            float oo = __shfl(nl, gbase | 6);
            if (lane < 2) {
                cst = ff * cst + nl * gg;
                hstage[wv * 2 + lane] = oo * tanh_fast(cst);
            }
            if (lane == 0)
                __hip_atomic_store(&flags[wv * 16], (unsigned)(t + 1),
                                   __ATOMIC_RELEASE, __HIP_MEMORY_SCOPE_WORKGROUP);
            if (wv == 0) {   // publisher: spin flags, xout + full-line publish
                while (__hip_atomic_load(&flags[fi * 16], __ATOMIC_ACQUIRE,
                                         __HIP_MEMORY_SCOPE_WORKGROUP) < (unsigned)(t + 1)) {}
                if (lane < 16) {
                    float h = hstage[lane];
                    xout[(size_t)t * 512 + w * 16 + lane] = h;
                    u64 word = ((u64)(tag1 + (unsigned)t + 1u) << 32) |
                               (u64)__float_as_uint(h);
                    __hip_atomic_store(&hbuf1[(t & 1) * 512 + w * 16 + lane], word,
                                       __ATOMIC_RELAXED, __HIP_MEMORY_SCOPE_AGENT);
                }
            }
            if (t + 1 < T) {
                // merged poll: issue all 16 loads, verify h1(t) (late) first
                const u64 want1 = (u64)(tag1 + (unsigned)t + 1u);
                const u64 want0 = (u64)(tag0 + (unsigned)t + 2u);
                const u64* b1p = &hbuf1[(size_t)(t & 1) * 512 + lane];
                const u64* b0p = &hfull[(size_t)(t + 1) * 512 + lane];
                u64 v1[8], v0[8];
#pragma unroll
                for (int k = 0; k < 8; k++)
                    v1[k] = __hip_atomic_load(b1p + k * 64, __ATOMIC_RELAXED,
                                              __HIP_MEMORY_SCOPE_AGENT);
#pragma unroll
                for (int k = 0; k < 8; k++)
                    v0[k] = __hip_atomic_load(b0p + k * 64, __ATOMIC_RELAXED,
                                              __HIP_MEMORY_SCOPE_AGENT);
                float* dst_ = &priv[p ^ 1][wv][0];
#pragma unroll
                for (int k = 0; k < 8; k++) {
                    while ((v1[k] >> 32) != want1)
                        v1[k] = __hip_atomic_load(b1p + k * 64, __ATOMIC_RELAXED,
                                                  __HIP_MEMORY_SCOPE_AGENT);
                    dst_[(8 + k) * 68 + lane] = __uint_as_float((unsigned)v1[k]);
                }
#pragma unroll
                for (int k = 0; k < 8; k++) {
                    while ((v0[k] >> 32) != want0)
                        v0[k] = __hip_atomic_load(b0p + k * 64, __ATOMIC_RELAXED,
                                                  __HIP_MEMORY_SCOPE_AGENT);
                    dst_[k * 68 + lane] = __uint_as_float((unsigned)v0[k]);
                }
                __threadfence_block();
                p ^= 1;
            }
        }
    }
}

// ---------------------------------------------------------------------------
__global__ void relu_ip(float* __restrict__ x, int n)
{
    int i = blockIdx.x * blockDim.x + threadIdx.x;
    if (i < n) x[i] = fmaxf(x[i], 0.0f);
}

__global__ void cbf_head(const float* __restrict__ xc, const float* __restrict__ w,
                         const float* __restrict__ b, float* __restrict__ out)
{
    int i = blockIdx.x, tid = threadIdx.x;
    const float* xr = xc + (size_t)i * FDIM;
    float acc = 0.0f;
    for (int d = tid; d < FDIM; d += 64) acc += fmaxf(xr[d], 0.0f) * w[d];
    for (int off = 32; off; off >>= 1) acc += __shfl_down(acc, off);
    if (tid == 0) out[i] = acc + b[0];
}

__global__ void zero_u64(u64* __restrict__ p, int n)
{
    int i = blockIdx.x * blockDim.x + threadIdx.x;
    int stride = gridDim.x * blockDim.x;
    for (; i < n; i += stride) p[i] = 0ull;
}

// ---------------------------------------------------------------------------
extern "C" void kernel_launch(void* const* d_in, const int* in_sizes, int n_in,
                              void* d_out, int out_size, void* d_ws, size_t ws_size,
                              hipStream_t stream)
{
    const float* x      = (const float*)d_in[0];
    const float* states = (const float*)d_in[1];
    const int*   src    = (const int*)d_in[2];
    const int*   dst    = (const int*)d_in[3];
    const float* phi_w0 = (const float*)d_in[4];
    const float* phi_b0 = (const float*)d_in[5];
    const float* phi_w1 = (const float*)d_in[6];
    const float* phi_b1 = (const float*)d_in[7];
    const float* phi_w2 = (const float*)d_in[8];
    const float* phi_b2 = (const float*)d_in[9];
    const float* tq_w = (const float*)d_in[10]; const float* tq_b = (const float*)d_in[11];
    const float* tk_w = (const float*)d_in[12]; const float* tk_b = (const float*)d_in[13];
    const float* tv_w = (const float*)d_in[14]; const float* tv_b = (const float*)d_in[15];
    const float* ts_w = (const float*)d_in[16]; const float* ts_b = (const float*)d_in[17];
    const float* wih0 = (const float*)d_in[18]; const float* whh0 = (const float*)d_in[19];
    const float* b0   = (const float*)d_in[20];
    const float* wih1 = (const float*)d_in[21]; const float* whh1 = (const float*)d_in[22];
    const float* b1   = (const float*)d_in[23];
    const float* cbf_w = (const float*)d_in[24]; const float* cbf_b = (const float*)d_in[25];

    float* ws = (float*)d_ws;
    size_t off = 0;
    auto alloc = [&](size_t n) { float* p = ws + off; off += n; return p; };
    float* xA     = alloc((size_t)NA * FDIM);
    float* xB     = alloc((size_t)NA * FDIM);
    float* phi    = alloc((size_t)NA * FDIM);
    float* qb     = alloc((size_t)NA * FDIM);
    float* kb     = alloc((size_t)NA * FDIM);
    float* vb     = alloc((size_t)NA * FDIM);
    float* aggr   = alloc((size_t)NA * FDIM);
    float* pre    = alloc((size_t)NA * GDIM);
    float* logits = alloc(NA);
    float* mb     = alloc(NA);
    float* ssum   = alloc(NA);
    float* ebuf   = alloc(NA);
    const int HFULL_WORDS = NA * 512;       // 2,097,152 u64
    u64* hfull = (u64*)alloc((size_t)2 * (HFULL_WORDS + 1024));
    u64* hbuf1 = hfull + HFULL_WORDS;

    float* out_x   = (float*)d_out;
    float* out_cbf = out_x + (size_t)NA * FDIM;

    zero_u64<<<2048, 256, 0, stream>>>(hfull, HFULL_WORDS + 1024);

    const float* xin = x;
    for (int l = 0; l < 4; l++) {
        float* xout = (l == 3) ? out_x : ((l & 1) ? xB : xA);

        phi_fused<<<NA, 256, 0, stream>>>(xin, states, src, dst,
            phi_w0 + (size_t)l * 518 * HID, phi_b0 + l * HID,
            phi_w1 + (size_t)l * HID * HID, phi_b1 + l * HID,
            phi_w2 + (size_t)l * HID * FDIM, phi_b2 + l * FDIM, phi);

        // fused Q/K/V/S: one dispatch, blockIdx.z picks weights/bias/output
        {
            Ptrs4 p;
            p.B[0] = tq_w + (size_t)l * FDIM * FDIM; p.bias[0] = tq_b + l * FDIM; p.C[0] = qb;
            p.B[1] = tk_w + (size_t)l * FDIM * FDIM; p.bias[1] = tk_b + l * FDIM; p.C[1] = kb;
            p.B[2] = tv_w + (size_t)l * FDIM * FDIM; p.bias[2] = tv_b + l * FDIM; p.C[2] = vb;
            p.B[3] = ts_w + (size_t)l * FDIM * FDIM; p.bias[3] = ts_b + l * FDIM; p.C[3] = aggr;
            gemm128<<<dim3(FDIM / 128, NA / 128, 4), 256, 0, stream>>>(
                phi, FDIM, phi, FDIM, FDIM, p, NA, FDIM, FDIM);
        }

        att_init<<<NA / 256, 256, 0, stream>>>(mb, ssum);
        att_logits<<<NA, 64, 0, stream>>>(qb, kb, src, dst, logits, mb);
        att_expsum<<<NA / 256, 256, 0, stream>>>(logits, mb, dst, ebuf, ssum);
        att_scatter<<<NA, 256, 0, stream>>>(vb, src, dst, ebuf, ssum, aggr);

        // pre0 = [aggr | xin] @ wih0 + b0
        {
            Ptrs4 p;
            p.B[0] = wih0 + (size_t)l * 1024 * GDIM; p.bias[0] = b0 + (size_t)l * GDIM; p.C[0] = pre;
            p.B[1] = p.B[0]; p.bias[1] = p.bias[0]; p.C[1] = pre;
            p.B[2] = p.B[0]; p.bias[2] = p.bias[0]; p.C[2] = pre;
            p.B[3] = p.B[0]; p.bias[3] = p.bias[0]; p.C[3] = pre;
            gemm128<<<dim3(GDIM / 128, NA / 128, 1), 256, 0, stream>>>(
                aggr, FDIM, xin, FDIM, FDIM, p, NA, GDIM, 1024);
        }

        // fused, pipelined LSTM0+LSTM1 (pre1 GEMM folded into role B)
        lstm_pair<<<2 * LWG, 512, 0, stream>>>(pre,
            whh0 + (size_t)l * FDIM * GDIM,
            wih1 + (size_t)l * FDIM * GDIM,
            whh1 + (size_t)l * FDIM * GDIM,
            b1 + (size_t)l * GDIM,
            xout, hfull, hbuf1,
            (unsigned)(2 * l) * NA, (unsigned)(2 * l + 1) * NA, NA);

        if (l == 0 || l == 2)
            relu_ip<<<(NA * FDIM + 255) / 256, 256, 0, stream>>>(xout, NA * FDIM);
        xin = xout;
    }

    cbf_head<<<NA, 64, 0, stream>>>(out_x, cbf_w, cbf_b, out_cbf);
}

// Round 9
// 31940.314 us; speedup vs baseline: 1.9320x; 1.9320x over previous
//
#include <hip/hip_runtime.h>
#include <hip/hip_bf16.h>
#include <math.h>

// Problem constants (from reference)
#define NA   4096      // num agents / edges
#define FDIM 512
#define SDIM 6
#define HID  20
#define GDIM 2048      // 4*FDIM (LSTM gate width)
#define LWG  32        // WGs per LSTM role in the persistent pair kernel

typedef unsigned long long u64;

__device__ __forceinline__ float sigf(float x) { return 1.0f / (1.0f + __expf(-x)); }
__device__ __forceinline__ float tanh_fast(float x) {
    float e = __expf(2.0f * x);
    return 1.0f - 2.0f / (e + 1.0f);
}

// LDS-only barrier: drains lgkmcnt (LDS) but NOT vmcnt, so in-flight global
// prefetches / publish stores are not serialized at the barrier.
// (__syncthreads emits s_waitcnt vmcnt(0) lgkmcnt(0); s_barrier.)
__device__ __forceinline__ void barrier_lds() {
    asm volatile("s_waitcnt lgkmcnt(0)\n\ts_barrier" ::: "memory");
}

__device__ __forceinline__ void atomicMaxF(float* addr, float v) {
    if (v >= 0.0f) atomicMax((int*)addr, __float_as_int(v));
    else           atomicMin((unsigned int*)addr, __float_as_uint(v));
}

// ---------------------------------------------------------------------------
// phi MLP, fused per edge: msg = [xin[src] | states[src]-states[dst]] (518)
// ---------------------------------------------------------------------------
__global__ void __launch_bounds__(256)
phi_fused(const float* __restrict__ xin, const float* __restrict__ states,
          const int* __restrict__ src, const int* __restrict__ dst,
          const float* __restrict__ w0, const float* __restrict__ b0,
          const float* __restrict__ w1, const float* __restrict__ b1,
          const float* __restrict__ w2, const float* __restrict__ b2,
          float* __restrict__ phi)
{
    int e = blockIdx.x, tid = threadIdx.x;
    __shared__ float msgv[FDIM + SDIM];
    __shared__ float red[240];
    __shared__ float hb1[HID];
    __shared__ float hb2[HID];
    int s = src[e], d = dst[e];
    for (int i = tid; i < FDIM; i += 256) msgv[i] = xin[(size_t)s * FDIM + i];
    if (tid < SDIM) msgv[FDIM + tid] = states[s * SDIM + tid] - states[d * SDIM + tid];
    __syncthreads();
    if (tid < 240) {
        int col = tid / 12, sg = tid % 12;
        int k0 = sg * 44, k1 = min(FDIM + SDIM, k0 + 44);
        float acc = 0.0f;
        for (int k = k0; k < k1; k++) acc += msgv[k] * w0[k * HID + col];
        red[tid] = acc;
    }
    __syncthreads();
    if (tid < HID) {
        float a = b0[tid];
#pragma unroll
        for (int q = 0; q < 12; q++) a += red[tid * 12 + q];
        hb1[tid] = fmaxf(a, 0.0f);
    }
    __syncthreads();
    if (tid < HID) {
        float a = b1[tid];
#pragma unroll
        for (int k = 0; k < HID; k++) a += hb1[k] * w1[k * HID + tid];
        hb2[tid] = fmaxf(a, 0.0f);
    }
    __syncthreads();
    for (int c = tid; c < FDIM; c += 256) {
        float a = b2[c];
#pragma unroll
        for (int k = 0; k < HID; k++) a += hb2[k] * w2[k * FDIM + c];
        phi[(size_t)e * FDIM + c] = a;
    }
}

// ---------------------------------------------------------------------------
// fp32 tiled GEMM: C[M,N] = A[M,K] @ B[K,N] + bias[N]; A split at col splitA.
// 128x128 tile, 256 threads, 8x8 microtile. blockIdx.z picks (B,bias,C).
// ---------------------------------------------------------------------------
struct Ptrs4 {
    const float* B[4];
    const float* bias[4];
    float* C[4];
};

__global__ void __launch_bounds__(256)
gemm128(const float* __restrict__ A1, int lda1,
        const float* __restrict__ A2, int lda2, int splitA,
        Ptrs4 p, int M, int N, int K)
{
    __shared__ float a_lds[16][132];
    __shared__ float b_lds[16][132];
    const float* __restrict__ B    = p.B[blockIdx.z];
    const float* __restrict__ bias = p.bias[blockIdx.z];
    float* __restrict__ C          = p.C[blockIdx.z];
    const int tid = threadIdx.x;
    const int m0 = blockIdx.y * 128, n0 = blockIdx.x * 128;
    const int ar = tid >> 2, ak4 = (tid & 3) * 4;
    const int br = tid >> 5, bc4 = (tid & 31) * 4;
    const int ty = tid >> 4, tx = tid & 15;
    float acc[8][8] = {};

    for (int kt = 0; kt < K; kt += 16) {
        int ak = kt + ak4;
        if (ak < splitA) {
            const float* r0 = A1 + (size_t)(m0 + ar) * lda1 + ak;
            const float* r1 = A1 + (size_t)(m0 + ar + 64) * lda1 + ak;
            float4 a0 = *(const float4*)r0;
            float4 a1 = *(const float4*)r1;
            a_lds[ak4 + 0][ar] = a0.x; a_lds[ak4 + 1][ar] = a0.y;
            a_lds[ak4 + 2][ar] = a0.z; a_lds[ak4 + 3][ar] = a0.w;
            a_lds[ak4 + 0][ar + 64] = a1.x; a_lds[ak4 + 1][ar + 64] = a1.y;
            a_lds[ak4 + 2][ar + 64] = a1.z; a_lds[ak4 + 3][ar + 64] = a1.w;
        } else {
            int acol = ak - splitA;
            const float* r0 = A2 + (size_t)(m0 + ar) * lda2 + acol;
            const float* r1 = A2 + (size_t)(m0 + ar + 64) * lda2 + acol;
            float4 a0 = *(const float4*)r0;
            float4 a1 = *(const float4*)r1;
            a_lds[ak4 + 0][ar] = a0.x; a_lds[ak4 + 1][ar] = a0.y;
            a_lds[ak4 + 2][ar] = a0.z; a_lds[ak4 + 3][ar] = a0.w;
            a_lds[ak4 + 0][ar + 64] = a1.x; a_lds[ak4 + 1][ar + 64] = a1.y;
            a_lds[ak4 + 2][ar + 64] = a1.z; a_lds[ak4 + 3][ar + 64] = a1.w;
        }
        {
            float4 b0v = *(const float4*)(B + (size_t)(kt + br) * N + n0 + bc4);
            float4 b1v = *(const float4*)(B + (size_t)(kt + br + 8) * N + n0 + bc4);
            *(float4*)&b_lds[br][bc4] = b0v;
            *(float4*)&b_lds[br + 8][bc4] = b1v;
        }
        __syncthreads();
#pragma unroll
        for (int kk = 0; kk < 16; kk++) {
            float av[8], bv[8];
            *(float4*)&av[0] = *(const float4*)&a_lds[kk][ty * 4];
            *(float4*)&av[4] = *(const float4*)&a_lds[kk][64 + ty * 4];
            *(float4*)&bv[0] = *(const float4*)&b_lds[kk][tx * 4];
            *(float4*)&bv[4] = *(const float4*)&b_lds[kk][64 + tx * 4];
#pragma unroll
            for (int i = 0; i < 8; i++)
#pragma unroll
                for (int j = 0; j < 8; j++)
                    acc[i][j] += av[i] * bv[j];
        }
        __syncthreads();
    }

    float4 bb0 = *(const float4*)(bias + n0 + tx * 4);
    float4 bb1 = *(const float4*)(bias + n0 + 64 + tx * 4);
    const float bbs0[4] = { bb0.x, bb0.y, bb0.z, bb0.w };
    const float bbs1[4] = { bb1.x, bb1.y, bb1.z, bb1.w };
#pragma unroll
    for (int i = 0; i < 8; i++) {
        int row = m0 + ((i < 4) ? (ty * 4 + i) : (64 + ty * 4 + i - 4));
        float4 o0, o1;
        o0.x = acc[i][0] + bbs0[0]; o0.y = acc[i][1] + bbs0[1];
        o0.z = acc[i][2] + bbs0[2]; o0.w = acc[i][3] + bbs0[3];
        o1.x = acc[i][4] + bbs1[0]; o1.y = acc[i][5] + bbs1[1];
        o1.z = acc[i][6] + bbs1[2]; o1.w = acc[i][7] + bbs1[3];
        *(float4*)&C[(size_t)row * N + n0 + tx * 4] = o0;
        *(float4*)&C[(size_t)row * N + n0 + 64 + tx * 4] = o1;
    }
}

// ---------------------------------------------------------------------------
// attention (generic segment softmax; with dst=arange it is singleton/exact)
// ---------------------------------------------------------------------------
__global__ void att_init(float* __restrict__ m, float* __restrict__ ssum)
{
    int i = blockIdx.x * blockDim.x + threadIdx.x;
    if (i < NA) { m[i] = -INFINITY; ssum[i] = 0.0f; }
}

__global__ void att_logits(const float* __restrict__ q, const float* __restrict__ k,
                           const int* __restrict__ src, const int* __restrict__ dst,
                           float* __restrict__ logits, float* __restrict__ m)
{
    int e = blockIdx.x, tid = threadIdx.x;
    int s = src[e], d = dst[e];
    const float4* qr = (const float4*)(q + (size_t)d * FDIM);
    const float4* kr = (const float4*)(k + (size_t)s * FDIM);
    float acc = 0.0f;
    for (int i = tid; i < FDIM / 4; i += 64) {
        float4 a = qr[i], b = kr[i];
        acc += a.x * b.x + a.y * b.y + a.z * b.z + a.w * b.w;
    }
    for (int off = 32; off; off >>= 1) acc += __shfl_down(acc, off);
    if (tid == 0) {
        float v = acc * 0.04419417382415922f;   // 1/sqrt(512)
        logits[e] = v;
        atomicMaxF(&m[d], v);
    }
}

__global__ void att_expsum(const float* __restrict__ logits, const float* __restrict__ m,
                           const int* __restrict__ dst,
                           float* __restrict__ ebuf, float* __restrict__ ssum)
{
    int e = blockIdx.x * blockDim.x + threadIdx.x;
    if (e < NA) {
        float v = __expf(logits[e] - m[dst[e]]);
        ebuf[e] = v;
        atomicAdd(&ssum[dst[e]], v);
    }
}

__global__ void att_scatter(const float* __restrict__ v, const int* __restrict__ src,
                            const int* __restrict__ dst, const float* __restrict__ ebuf,
                            const float* __restrict__ ssum, float* __restrict__ aggr)
{
    int e = blockIdx.x, tid = threadIdx.x;
    int s = src[e], d = dst[e];
    float alpha = ebuf[e] / ssum[d];
    const float* vr = v + (size_t)s * FDIM;
    float* ar = aggr + (size_t)d * FDIM;
    for (int c = tid; c < FDIM; c += 256) atomicAdd(&ar[c], alpha * vr[c]);
}

// ---------------------------------------------------------------------------
// Pipelined 2-layer LSTM scan (R7 structure + LDS-only barriers).
// 64 WGs x 512 threads. Wave-local compute (shfl k-reduce, parallel gate
// transcendentals) + FULL-LINE single-wave publish via LDS hstage funnel.
// In-loop barriers are lgkmcnt-only (barrier_lds): the pre0 prefetch and the
// publish stores stay in flight across them — they are consumed/ordered via
// compiler-inserted waitcnts / the polled address, not the barrier.
// Tag protocol (proven R2..R7): word = (tag + t + 1)<<32 | float bits.
// ---------------------------------------------------------------------------
__global__ void __launch_bounds__(512, 2)
lstm_pair(const float* __restrict__ pre0, const float* __restrict__ whh0,
          const float* __restrict__ wih1, const float* __restrict__ whh1,
          const float* __restrict__ b1,
          float* __restrict__ xout,
          u64* __restrict__ hfull,
          u64* __restrict__ hbuf1,
          unsigned int tag0, unsigned int tag1, int T)
{
    const int wg = blockIdx.x;
    const bool roleB = wg >= LWG;
    const int w = wg & (LWG - 1);
    const int tid = threadIdx.x;
    const int lane = tid & 63;
    const int wv = tid >> 6;               // wave 0..7
    const int c = lane & 7;                // gate-column slot
    const int seg = lane >> 3;             // k-segment 0..7
    const int gate = c >> 1;               // 0=i 1=f 2=g 3=o
    const int dimoff = c & 1;
    const int hd = w * 16 + wv * 2 + dimoff;   // owned h dim
    const int j = gate * 512 + hd;             // gate column index
    const bool selfWord = (tid >> 4) == w;     // poll word tid belongs to own WG

    __shared__ float buf[2][1088];         // 16 groups of 64, stride 68 (padded)
    __shared__ float hstage[16];
    for (int i = tid; i < 1088; i += 512) { buf[0][i] = 0.0f; buf[1][i] = 0.0f; }

    float wreg[128];
    if (!roleB) {
        const float* wc = whh0 + (size_t)(seg * 64) * GDIM + j;
#pragma unroll
        for (int kk = 0; kk < 64; kk++) wreg[kk] = wc[(size_t)kk * GDIM];
    } else {
        // concat [h0 ; h1] weight column: k<512 -> wih1, else whh1
#pragma unroll
        for (int kk = 0; kk < 128; kk++) {
            int k = seg * 128 + kk;
            wreg[kk] = (k < 512) ? wih1[(size_t)k * GDIM + j]
                                 : whh1[(size_t)(k - 512) * GDIM + j];
        }
    }
    __syncthreads();

    const int gbase = (lane & 56) | dimoff;   // shfl gather base

    if (!roleB) {
        float cst = 0.0f;
        float pre_nxt = pre0[j];
        int p = 0;
        for (int t = 0; t < T; t++) {
            const float* hb = &buf[p][seg * 68];
            float a0 = 0, a1 = 0, a2 = 0, a3 = 0;
#pragma unroll
            for (int kk = 0; kk < 64; kk += 4) {
                float4 hv = *(const float4*)(hb + kk);
                a0 += wreg[kk + 0] * hv.x;
                a1 += wreg[kk + 1] * hv.y;
                a2 += wreg[kk + 2] * hv.z;
                a3 += wreg[kk + 3] * hv.w;
            }
            float tot = (a0 + a1) + (a2 + a3);
            tot += __shfl_xor(tot, 8);
            tot += __shfl_xor(tot, 16);
            tot += __shfl_xor(tot, 32);
            tot += pre_nxt;
            if (t + 1 < T) pre_nxt = pre0[(size_t)(t + 1) * GDIM + j];  // prefetch
            float nl = (gate == 2) ? tanh_fast(tot) : sigf(tot);
            float ff = __shfl(nl, gbase | 2);
            float gg = __shfl(nl, gbase | 4);
            float oo = __shfl(nl, gbase | 6);
            if (lane < 2) {
                cst = ff * cst + nl * gg;       // nl = sig(i) on lanes 0,1
                hstage[wv * 2 + lane] = oo * tanh_fast(cst);
            }
            barrier_lds();                       // hstage complete (LDS only)
            if (tid < 16) {                      // wave 0: full-line publish
                u64 word = ((u64)(tag0 + (unsigned)t + 1u) << 32) |
                           (u64)__float_as_uint(hstage[tid]);
                __hip_atomic_store(&hfull[(size_t)t * 512 + w * 16 + tid], word,
                                   __ATOMIC_RELAXED, __HIP_MEMORY_SCOPE_AGENT);
            }
            if (t + 1 < T) {
                float hv_;
                if (selfWord) {
                    hv_ = hstage[tid & 15];
                } else {
                    u64 want = tag0 + (unsigned)t + 1u;
                    const u64* pp = &hfull[(size_t)t * 512 + tid];
                    u64 v = __hip_atomic_load(pp, __ATOMIC_RELAXED, __HIP_MEMORY_SCOPE_AGENT);
                    while ((v >> 32) != want)
                        v = __hip_atomic_load(pp, __ATOMIC_RELAXED, __HIP_MEMORY_SCOPE_AGENT);
                    hv_ = __uint_as_float((unsigned)v);
                }
                buf[p ^ 1][(tid >> 6) * 68 + (tid & 63)] = hv_;
                barrier_lds();                   // buf[p^1] complete (LDS only)
                p ^= 1;
            }
        }
    } else {
        float cst = 0.0f;
        float bias = b1[j];
        int p = 0;
        {   // prologue: poll h0(0) into buf[0] low groups; h1(-1)=0 already there
            u64 want = tag0 + 1u;
            const u64* pp = &hfull[tid];
            u64 v = __hip_atomic_load(pp, __ATOMIC_RELAXED, __HIP_MEMORY_SCOPE_AGENT);
            while ((v >> 32) != want)
                v = __hip_atomic_load(pp, __ATOMIC_RELAXED, __HIP_MEMORY_SCOPE_AGENT);
            buf[0][(tid >> 6) * 68 + (tid & 63)] = __uint_as_float((unsigned)v);
            barrier_lds();
        }
        for (int t = 0; t < T; t++) {
            const float* hb = &buf[p][seg * 136];   // two padded 64-groups
            float a0 = 0, a1 = 0, a2 = 0, a3 = 0;
#pragma unroll
            for (int kk = 0; kk < 64; kk += 4) {
                float4 hv = *(const float4*)(hb + kk);
                a0 += wreg[kk + 0] * hv.x;
                a1 += wreg[kk + 1] * hv.y;
                a2 += wreg[kk + 2] * hv.z;
                a3 += wreg[kk + 3] * hv.w;
            }
#pragma unroll
            for (int kk = 0; kk < 64; kk += 4) {
                float4 hv = *(const float4*)(hb + 68 + kk);
                a0 += wreg[64 + kk + 0] * hv.x;
                a1 += wreg[64 + kk + 1] * hv.y;
                a2 += wreg[64 + kk + 2] * hv.z;
                a3 += wreg[64 + kk + 3] * hv.w;
            }
            float tot = (a0 + a1) + (a2 + a3);
            tot += __shfl_xor(tot, 8);
            tot += __shfl_xor(tot, 16);
            tot += __shfl_xor(tot, 32);
            tot += bias;
            float nl = (gate == 2) ? tanh_fast(tot) : sigf(tot);
            float ff = __shfl(nl, gbase | 2);
            float gg = __shfl(nl, gbase | 4);
            float oo = __shfl(nl, gbase | 6);
            if (lane < 2) {
                cst = ff * cst + nl * gg;
                hstage[wv * 2 + lane] = oo * tanh_fast(cst);
            }
            barrier_lds();                       // hstage complete (LDS only)
            if (tid < 16) {                      // wave 0: publish FIRST, then xout
                float h = hstage[tid];
                u64 word = ((u64)(tag1 + (unsigned)t + 1u) << 32) |
                           (u64)__float_as_uint(h);
                __hip_atomic_store(&hbuf1[(t & 1) * 512 + w * 16 + tid], word,
                                   __ATOMIC_RELAXED, __HIP_MEMORY_SCOPE_AGENT);
                xout[(size_t)t * 512 + w * 16 + tid] = h;        // 64B line
            }
            if (t + 1 < T) {
                // merged polls: h0(t+1) [role A ahead, usually ready] then h1(t)
                float h0v, h1v;
                {
                    u64 want = tag0 + (unsigned)(t + 1) + 1u;
                    const u64* pp = &hfull[(size_t)(t + 1) * 512 + tid];
                    u64 v = __hip_atomic_load(pp, __ATOMIC_RELAXED, __HIP_MEMORY_SCOPE_AGENT);
                    while ((v >> 32) != want)
                        v = __hip_atomic_load(pp, __ATOMIC_RELAXED, __HIP_MEMORY_SCOPE_AGENT);
                    h0v = __uint_as_float((unsigned)v);
                }
                if (selfWord) {
                    h1v = hstage[tid & 15];
                } else {
                    u64 want = tag1 + (unsigned)t + 1u;
                    const u64* pp = &hbuf1[(t & 1) * 512 + tid];
                    u64 v = __hip_atomic_load(pp, __ATOMIC_RELAXED, __HIP_MEMORY_SCOPE_AGENT);
                    while ((v >> 32) != want)
                        v = __hip_atomic_load(pp, __ATOMIC_RELAXED, __HIP_MEMORY_SCOPE_AGENT);
                    h1v = __uint_as_float((unsigned)v);
                }
                buf[p ^ 1][(tid >> 6) * 68 + (tid & 63)] = h0v;
                buf[p ^ 1][(8 + (tid >> 6)) * 68 + (tid & 63)] = h1v;
                barrier_lds();                   // buf[p^1] complete (LDS only)
                p ^= 1;
            }
        }
    }
}

// ---------------------------------------------------------------------------
__global__ void relu_ip(float* __restrict__ x, int n)
{
    int i = blockIdx.x * blockDim.x + threadIdx.x;
    if (i < n) x[i] = fmaxf(x[i], 0.0f);
}

__global__ void cbf_head(const float* __restrict__ xc, const float* __restrict__ w,
                         const float* __restrict__ b, float* __restrict__ out)
{
    int i = blockIdx.x, tid = threadIdx.x;
    const float* xr = xc + (size_t)i * FDIM;
    float acc = 0.0f;
    for (int d = tid; d < FDIM; d += 64) acc += fmaxf(xr[d], 0.0f) * w[d];
    for (int off = 32; off; off >>= 1) acc += __shfl_down(acc, off);
    if (tid == 0) out[i] = acc + b[0];
}

__global__ void zero_u64(u64* __restrict__ p, int n)
{
    int i = blockIdx.x * blockDim.x + threadIdx.x;
    int stride = gridDim.x * blockDim.x;
    for (; i < n; i += stride) p[i] = 0ull;
}

// ---------------------------------------------------------------------------
extern "C" void kernel_launch(void* const* d_in, const int* in_sizes, int n_in,
                              void* d_out, int out_size, void* d_ws, size_t ws_size,
                              hipStream_t stream)
{
    const float* x      = (const float*)d_in[0];
    const float* states = (const float*)d_in[1];
    const int*   src    = (const int*)d_in[2];
    const int*   dst    = (const int*)d_in[3];
    const float* phi_w0 = (const float*)d_in[4];
    const float* phi_b0 = (const float*)d_in[5];
    const float* phi_w1 = (const float*)d_in[6];
    const float* phi_b1 = (const float*)d_in[7];
    const float* phi_w2 = (const float*)d_in[8];
    const float* phi_b2 = (const float*)d_in[9];
    const float* tq_w = (const float*)d_in[10]; const float* tq_b = (const float*)d_in[11];
    const float* tk_w = (const float*)d_in[12]; const float* tk_b = (const float*)d_in[13];
    const float* tv_w = (const float*)d_in[14]; const float* tv_b = (const float*)d_in[15];
    const float* ts_w = (const float*)d_in[16]; const float* ts_b = (const float*)d_in[17];
    const float* wih0 = (const float*)d_in[18]; const float* whh0 = (const float*)d_in[19];
    const float* b0   = (const float*)d_in[20];
    const float* wih1 = (const float*)d_in[21]; const float* whh1 = (const float*)d_in[22];
    const float* b1   = (const float*)d_in[23];
    const float* cbf_w = (const float*)d_in[24]; const float* cbf_b = (const float*)d_in[25];

    float* ws = (float*)d_ws;
    size_t off = 0;
    auto alloc = [&](size_t n) { float* p = ws + off; off += n; return p; };
    float* xA     = alloc((size_t)NA * FDIM);
    float* xB     = alloc((size_t)NA * FDIM);
    float* phi    = alloc((size_t)NA * FDIM);
    float* qb     = alloc((size_t)NA * FDIM);
    float* kb     = alloc((size_t)NA * FDIM);
    float* vb     = alloc((size_t)NA * FDIM);
    float* aggr   = alloc((size_t)NA * FDIM);
    float* pre    = alloc((size_t)NA * GDIM);
    float* logits = alloc(NA);
    float* mb     = alloc(NA);
    float* ssum   = alloc(NA);
    float* ebuf   = alloc(NA);
    const int HFULL_WORDS = NA * 512;       // 2,097,152 u64
    u64* hfull = (u64*)alloc((size_t)2 * (HFULL_WORDS + 1024));
    u64* hbuf1 = hfull + HFULL_WORDS;

    float* out_x   = (float*)d_out;
    float* out_cbf = out_x + (size_t)NA * FDIM;

    zero_u64<<<2048, 256, 0, stream>>>(hfull, HFULL_WORDS + 1024);

    const float* xin = x;
    for (int l = 0; l < 4; l++) {
        float* xout = (l == 3) ? out_x : ((l & 1) ? xB : xA);

        phi_fused<<<NA, 256, 0, stream>>>(xin, states, src, dst,
            phi_w0 + (size_t)l * 518 * HID, phi_b0 + l * HID,
            phi_w1 + (size_t)l * HID * HID, phi_b1 + l * HID,
            phi_w2 + (size_t)l * HID * FDIM, phi_b2 + l * FDIM, phi);

        // fused Q/K/V/S: one dispatch, blockIdx.z picks weights/bias/output
        {
            Ptrs4 p;
            p.B[0] = tq_w + (size_t)l * FDIM * FDIM; p.bias[0] = tq_b + l * FDIM; p.C[0] = qb;
            p.B[1] = tk_w + (size_t)l * FDIM * FDIM; p.bias[1] = tk_b + l * FDIM; p.C[1] = kb;
            p.B[2] = tv_w + (size_t)l * FDIM * FDIM; p.bias[2] = tv_b + l * FDIM; p.C[2] = vb;
            p.B[3] = ts_w + (size_t)l * FDIM * FDIM; p.bias[3] = ts_b + l * FDIM; p.C[3] = aggr;
            gemm128<<<dim3(FDIM / 128, NA / 128, 4), 256, 0, stream>>>(
                phi, FDIM, phi, FDIM, FDIM, p, NA, FDIM, FDIM);
        }

        att_init<<<NA / 256, 256, 0, stream>>>(mb, ssum);
        att_logits<<<NA, 64, 0, stream>>>(qb, kb, src, dst, logits, mb);
        att_expsum<<<NA / 256, 256, 0, stream>>>(logits, mb, dst, ebuf, ssum);
        att_scatter<<<NA, 256, 0, stream>>>(vb, src, dst, ebuf, ssum, aggr);

        // pre0 = [aggr | xin] @ wih0 + b0
        {
            Ptrs4 p;
            p.B[0] = wih0 + (size_t)l * 1024 * GDIM; p.bias[0] = b0 + (size_t)l * GDIM; p.C[0] = pre;
            p.B[1] = p.B[0]; p.bias[1] = p.bias[0]; p.C[1] = pre;
            p.B[2] = p.B[0]; p.bias[2] = p.bias[0]; p.C[2] = pre;
            p.B[3] = p.B[0]; p.bias[3] = p.bias[0]; p.C[3] = pre;
            gemm128<<<dim3(GDIM / 128, NA / 128, 1), 256, 0, stream>>>(
                aggr, FDIM, xin, FDIM, FDIM, p, NA, GDIM, 1024);
        }

        // fused, pipelined LSTM0+LSTM1 (pre1 GEMM folded into role B)
        lstm_pair<<<2 * LWG, 512, 0, stream>>>(pre,
            whh0 + (size_t)l * FDIM * GDIM,
            wih1 + (size_t)l * FDIM * GDIM,
            whh1 + (size_t)l * FDIM * GDIM,
            b1 + (size_t)l * GDIM,
            xout, hfull, hbuf1,
            (unsigned)(2 * l) * NA, (unsigned)(2 * l + 1) * NA, NA);

        if (l == 0 || l == 2)
            relu_ip<<<(NA * FDIM + 255) / 256, 256, 0, stream>>>(xout, NA * FDIM);
        xin = xout;
    }

    cbf_head<<<NA, 64, 0, stream>>>(out_x, cbf_w, cbf_b, out_cbf);
}